// Round 9
// baseline (1476.110 us; speedup 1.0000x reference)
//
#include <hip/hip_runtime.h>
#include <stdint.h>

#define DEVI __device__ __forceinline__

typedef __attribute__((ext_vector_type(4))) int    i32x4;
typedef __attribute__((ext_vector_type(4))) float  f32x4;
typedef __attribute__((ext_vector_type(8))) __bf16 bf16x8;

static constexpr int BB = 4, NN = 2048, KK = 32, PP = NN * KK;  // P per batch
static constexpr float GEPS = 1e-5f;

DEVI unsigned short f2bf(float f) {
  unsigned u = __builtin_bit_cast(unsigned, f);
  return (unsigned short)((u + 0x7FFFu + ((u >> 16) & 1u)) >> 16);
}
DEVI float bf2f(unsigned short h) {
  unsigned u = (unsigned)h << 16;
  return __builtin_bit_cast(float, u);
}
DEVI uint2 pack4(float a, float b, float c, float d) {
  return make_uint2((unsigned)f2bf(a) | ((unsigned)f2bf(b) << 16),
                    (unsigned)f2bf(c) | ((unsigned)f2bf(d) << 16));
}
DEVI void mfma16(f32x4& d, i32x4 a, i32x4 b) {
  // A[m=lane&15][k=8*(lane>>4)+j], B[k][n=lane&15], D[m=(lane>>4)*4+reg][n=lane&15].
  d = __builtin_amdgcn_mfma_f32_16x16x32_bf16(
      __builtin_bit_cast(bf16x8, a), __builtin_bit_cast(bf16x8, b), d, 0, 0, 0);
}

// ---------------- prep: convert f32 weights to bf16 ----------------
__global__ void prep_kern(const float* Wfc, const float* Wgc, const float* Wfo,
                          unsigned short* dWfc, unsigned short* dWgc, unsigned short* dWfo) {
  int i = blockIdx.x * 256 + threadIdx.x;
  if (i < 16384)       dWfc[i] = f2bf(Wfc[i]);
  else if (i < 32768)  dWgc[i - 16384] = f2bf(Wgc[i - 16384]);
  else if (i < 98304)  dWfo[i - 32768] = f2bf(Wfo[i - 32768]);
}

// ---------------- wave-cohort fused GEMM (raw s_barrier, no drains) --------
// out[b][p][COUT](bf16) = act(W[COUT][CIN] @ in[b][CIN][p] + bias)
// 512 thr = 8 waves; wave owns MW out-channels; all waves walk the SAME
// position tiles. One raw s_barrier per tile bounds wave drift so the 8
// waves' IDENTICAL B-loads hit L1/L2 instead of refetching HBM (R8 disease:
// unbounded drift -> FETCH = 8x input). s_barrier has no waitcnt drain, so
// loads stay in flight across it. LDS slices are wave-private (transpose
// buffer for coalesced 64B stores); no inter-wave data deps.
// MODE 0: srcA = f32 channel-major [b][CIN][P]  (8 dword loads per ks, packed)
// MODE 1: srcA = r1 bf16 [b][n][128] (k-broadcast), srcB = r2 bf16 [b][p][128]
template<int CIN, int COUT, int MODE, bool RELU>
__global__ __launch_bounds__(512)
__attribute__((amdgpu_waves_per_eu(4, 4)))
void wgemm_kern(const void* __restrict__ srcA, const void* __restrict__ srcB,
                const unsigned short* __restrict__ Wmat, const float* __restrict__ bias,
                unsigned short* __restrict__ out, float* __restrict__ stats, int group_base,
                int P, int tiles_per_b, int nblk) {
  constexpr int MW = (COUT == 256) ? 32 : 16;  // out-channels per wave
  constexpr int MF = MW / 16;                  // m-fragments (2 or 1)
  constexpr int KS = CIN / 32;                 // k-steps
  __shared__ unsigned short osl[8 * 16 * MW];  // per-wave output slices

  const int tid = threadIdx.x;
  const int lane = tid & 63, w = tid >> 6;
  const int l15 = lane & 15, lg = lane >> 4;
  const int b = blockIdx.x / nblk, blk = blockIdx.x % nblk;
  const int tpb = tiles_per_b / nblk;

  const unsigned short* Wb = (MODE == 1) ? (Wmat + (size_t)b * COUT * CIN) : Wmat;
  const float* biasb = (MODE == 1) ? (bias + b * COUT) : bias;
  const float* src0 = (const float*)srcA + (size_t)b * CIN * P;
  const unsigned short* r1b = (const unsigned short*)srcA + (size_t)b * NN * 128;
  const unsigned short* r2b = (const unsigned short*)srcB + (size_t)b * PP * 128;

  // W fragments resident for the whole kernel
  i32x4 a[KS][MF];
#pragma unroll
  for (int ks = 0; ks < KS; ++ks)
#pragma unroll
    for (int mf = 0; mf < MF; ++mf)
      a[ks][mf] = *(const i32x4*)(Wb + (size_t)(w * MW + mf * 16 + l15) * CIN + ks * 32 + lg * 8);

  f32x4 bi[MF];
#pragma unroll
  for (int mf = 0; mf < MF; ++mf)
    bi[mf] = *(const f32x4*)(biasb + w * MW + mf * 16 + lg * 4);

  float ssum[MF], ssq[MF];
#pragma unroll
  for (int mf = 0; mf < MF; ++mf) { ssum[mf] = 0.f; ssq[mf] = 0.f; }

  unsigned short* slice = &osl[w * 16 * MW];

  for (int t = blk * tpb; t < (blk + 1) * tpb; ++t) {
    __builtin_amdgcn_s_barrier();  // align waves; NO waitcnt drain
    const int p0 = t * 16;

    f32x4 acc[MF];
#pragma unroll
    for (int mf = 0; mf < MF; ++mf) acc[mf] = f32x4{0.f, 0.f, 0.f, 0.f};

#pragma unroll
    for (int ks = 0; ks < KS; ++ks) {
      i32x4 bf;
      if constexpr (MODE == 0) {
        float v[8];
#pragma unroll
        for (int j = 0; j < 8; ++j)
          v[j] = src0[(size_t)(ks * 32 + lg * 8 + j) * (size_t)P + p0 + l15];
        uint2 lo = pack4(v[0], v[1], v[2], v[3]);
        uint2 hi = pack4(v[4], v[5], v[6], v[7]);
        bf = i32x4{(int)lo.x, (int)lo.y, (int)hi.x, (int)hi.y};
      } else {
        if (ks < KS / 2) {
          // r1 part: same n for all 16 positions of the tile (broadcast)
          bf = *(const i32x4*)(r1b + (size_t)(p0 >> 5) * 128 + ks * 32 + lg * 8);
        } else {
          bf = *(const i32x4*)(r2b + (size_t)(p0 + l15) * 128 + (ks - KS / 2) * 32 + lg * 8);
        }
      }
#pragma unroll
      for (int mf = 0; mf < MF; ++mf) mfma16(acc[mf], a[ks][mf], bf);
    }

    // epilogue: bias (+relu), stats, transpose via private LDS slice,
    // coalesced 64B-segment global stores. (All LDS offsets in shorts.)
#pragma unroll
    for (int mf = 0; mf < MF; ++mf) {
      float y0 = acc[mf][0] + bi[mf][0];
      float y1 = acc[mf][1] + bi[mf][1];
      float y2 = acc[mf][2] + bi[mf][2];
      float y3 = acc[mf][3] + bi[mf][3];
      if (RELU) {
        y0 = fmaxf(y0, 0.f); y1 = fmaxf(y1, 0.f);
        y2 = fmaxf(y2, 0.f); y3 = fmaxf(y3, 0.f);
      }
      ssum[mf] += y0 + y1 + y2 + y3;
      ssq[mf] += y0 * y0 + y1 * y1 + y2 * y2 + y3 * y3;
      // row = pos l15 (MW shorts); logical 4-short chunk c, XOR-swizzled
      if constexpr (MW == 32) {
        const int c = (mf * 4 + lg) ^ (l15 & 6);  // XOR even bits: 16B pairs stay adjacent
        *(uint2*)&slice[l15 * 32 + c * 4] = pack4(y0, y1, y2, y3);
      } else {
        const int c = lg ^ (l15 & 2);
        *(uint2*)&slice[l15 * 16 + c * 4] = pack4(y0, y1, y2, y3);
      }
    }
    // read back transposed + store (same wave; DS ops ordered by data dependence)
    if constexpr (MW == 32) {
      const int pos = lane >> 2, q = lane & 3;          // 16B chunk q = 8 ch
      const int qs = q ^ ((pos & 6) >> 1);
      uint4 val = *(const uint4*)&slice[pos * 32 + qs * 8];
      *(uint4*)(out + ((size_t)b * P + p0 + pos) * COUT + w * 32 + q * 8) = val;
    } else {
      const int pos = lane >> 2, cc = lane & 3;         // 8B chunk cc = 4 ch
      const int cs = cc ^ (pos & 2);
      uint2 val = *(const uint2*)&slice[pos * 16 + cs * 4];
      *(uint2*)(out + ((size_t)b * P + p0 + pos) * COUT + w * 16 + cc * 4) = val;
    }
  }

  // stats reduction -> global atomics
#pragma unroll
  for (int mf = 0; mf < MF; ++mf) {
    float s = ssum[mf], q = ssq[mf];
#pragma unroll
    for (int d = 1; d < 16; d <<= 1) { s += __shfl_xor(s, d); q += __shfl_xor(q, d); }
    if (l15 == 0) {
      int g = group_base + ((w * MW + mf * 16 + lg * 4) >> 3);
      atomicAdd(&stats[(b * 32 + g) * 2 + 0], s);
      atomicAdd(&stats[(b * 32 + g) * 2 + 1], q);
    }
  }
}

// ---------------- fold kernels ----------------
__global__ void fold1_kern(const float* st1, const float* g1, const float* be1,
                           const float* W_w1, const float* b_w1,
                           unsigned short* W1p, float* b1p) {
  int b = blockIdx.x, tid = threadIdx.x;
  __shared__ float s_l[256], t_l[256];
  {
    int c = tid, g = c >> 3;
    float cnt = (g < 16) ? (8.f * NN) : (8.f * NN * KK);
    float su = st1[(b * 32 + g) * 2], sq = st1[(b * 32 + g) * 2 + 1];
    float mean = su / cnt;
    float var = fmaxf(sq / cnt - mean * mean, 0.f);
    float s = g1[c] * rsqrtf(var + GEPS);
    s_l[c] = s; t_l[c] = be1[c] - mean * s;
  }
  __syncthreads();
  int o = tid;
  float acc = b_w1[o];
  for (int c4 = 0; c4 < 64; ++c4) {
    float4 wv = *(const float4*)(W_w1 + o * 256 + c4 * 4);
    *(uint2*)&W1p[((size_t)b * 256 + o) * 256 + c4 * 4] =
        pack4(wv.x * s_l[c4 * 4], wv.y * s_l[c4 * 4 + 1],
              wv.z * s_l[c4 * 4 + 2], wv.w * s_l[c4 * 4 + 3]);
    acc += wv.x * t_l[c4 * 4] + wv.y * t_l[c4 * 4 + 1] +
           wv.z * t_l[c4 * 4 + 2] + wv.w * t_l[c4 * 4 + 3];
  }
  b1p[b * 256 + o] = acc;
}

__global__ void fold23_kern(const float* st2, const float* st3,
                            const float* g2, const float* be2,
                            const float* W_w2, const float* b_w2,
                            const float* g3, const float* be3,
                            unsigned short* W2p, float* b2p, float* s3t3) {
  int b = blockIdx.x, tid = threadIdx.x;
  __shared__ float s_l[256], t_l[256];
  {
    int c = tid, g = c >> 3;
    float cnt = 8.f * NN * KK;
    float su = st2[(b * 32 + g) * 2], sq = st2[(b * 32 + g) * 2 + 1];
    float mean = su / cnt;
    float var = fmaxf(sq / cnt - mean * mean, 0.f);
    float s = g2[c] * rsqrtf(var + GEPS);
    s_l[c] = s; t_l[c] = be2[c] - mean * s;

    float su3 = st3[(b * 32 + g) * 2], sq3 = st3[(b * 32 + g) * 2 + 1];
    float mean3 = su3 / cnt;
    float var3 = fmaxf(sq3 / cnt - mean3 * mean3, 0.f);
    float s3 = g3[c] * rsqrtf(var3 + GEPS);
    s3t3[(b * 256 + c) * 2 + 0] = s3;
    s3t3[(b * 256 + c) * 2 + 1] = be3[c] - mean3 * s3;
  }
  __syncthreads();
  int o = tid;
  float acc = b_w2[o];
  for (int c4 = 0; c4 < 64; ++c4) {
    float4 wv = *(const float4*)(W_w2 + o * 256 + c4 * 4);
    *(uint2*)&W2p[((size_t)b * 256 + o) * 256 + c4 * 4] =
        pack4(wv.x * s_l[c4 * 4], wv.y * s_l[c4 * 4 + 1],
              wv.z * s_l[c4 * 4 + 2], wv.w * s_l[c4 * 4 + 3]);
    acc += wv.x * t_l[c4 * 4] + wv.y * t_l[c4 * 4 + 1] +
           wv.z * t_l[c4 * 4 + 2] + wv.w * t_l[c4 * 4 + 3];
  }
  b2p[b * 256 + o] = acc;
}

// ---------------- K5: wave-cohort scores + softmax + weighted sum ----------------
// 32-pos tiles (= one n). Raw s_barrier per tile bounds drift -> the 8 waves'
// identical x2 A-frag loads hit L1/L2. W2 resident; gor staged per-WAVE into a
// private LDS slice (32 pos x 32 ch, offsets in shorts) via coalesced b128 loads.
__global__ __launch_bounds__(512)
__attribute__((amdgpu_waves_per_eu(4, 4)))
void k5_kern(const unsigned short* __restrict__ x2t, const unsigned short* __restrict__ gor,
             const unsigned short* __restrict__ W2p, const float* __restrict__ b2p,
             const float* __restrict__ s3t3, const int* __restrict__ count,
             float* __restrict__ out, int tiles_per_b, int nblk) {
  __shared__ unsigned short gsl[8 * 32 * 32];  // per-wave 32pos x 32ch slices
  const int tid = threadIdx.x, lane = tid & 63, w = tid >> 6;
  const int l15 = lane & 15, lg = lane >> 4;
  const int b = blockIdx.x / nblk, blk = blockIdx.x % nblk;
  const int tpb = tiles_per_b / nblk;
  const int wch = w * 32;

  const unsigned short* Wb = W2p + (size_t)b * 65536;

  i32x4 wb[8][2];
#pragma unroll
  for (int ks = 0; ks < 8; ++ks)
#pragma unroll
    for (int of = 0; of < 2; ++of)
      wb[ks][of] = *(const i32x4*)(Wb + (size_t)(wch + of * 16 + l15) * 256 + ks * 32 + lg * 8);

  float bia[2], s3v[2], t3v[2];
#pragma unroll
  for (int of = 0; of < 2; ++of) {
    int o = wch + of * 16 + l15;
    bia[of] = b2p[b * 256 + o];
    s3v[of] = s3t3[(b * 256 + o) * 2 + 0];
    t3v[of] = s3t3[(b * 256 + o) * 2 + 1];
  }

  const unsigned short* xb = x2t + (size_t)b * PP * 256;
  const unsigned short* gb = gor + (size_t)b * PP * 256;
  unsigned short* slice = &gsl[w * 32 * 32];

  for (int t = blk * tpb; t < (blk + 1) * tpb; ++t) {
    __builtin_amdgcn_s_barrier();  // align waves; NO waitcnt drain
    const int p0 = t * 32, n = t;

    // stage gor slice [32 pos][32 ch]: row = 32 shorts; 8-short chunk q,
    // physical chunk qs = q ^ ((pos&6)>>1)
#pragma unroll
    for (int h = 0; h < 2; ++h) {
      const int pos = h * 16 + (lane >> 2), q = lane & 3;
      uint4 gv = *(const uint4*)(gb + (size_t)(p0 + pos) * 256 + wch + q * 8);
      const int qs = q ^ ((pos & 6) >> 1);
      *(uint4*)&slice[pos * 32 + qs * 8] = gv;
    }

    f32x4 acc[2][2];  // [pf][of]
#pragma unroll
    for (int pf = 0; pf < 2; ++pf)
#pragma unroll
      for (int of = 0; of < 2; ++of) acc[pf][of] = f32x4{0.f, 0.f, 0.f, 0.f};

#pragma unroll
    for (int ks = 0; ks < 8; ++ks) {
      i32x4 af[2];
#pragma unroll
      for (int pf = 0; pf < 2; ++pf)
        af[pf] = *(const i32x4*)(xb + (size_t)(p0 + pf * 16 + l15) * 256 + ks * 32 + lg * 8);
#pragma unroll
      for (int pf = 0; pf < 2; ++pf)
#pragma unroll
        for (int of = 0; of < 2; ++of) mfma16(acc[pf][of], af[pf], wb[ks][of]);
    }

    const int cnt = max(count[b * NN + n], 1);
#pragma unroll
    for (int of = 0; of < 2; ++of) {
      const int o = wch + of * 16 + l15;
      float sc[2][4];
#pragma unroll
      for (int pf = 0; pf < 2; ++pf)
#pragma unroll
        for (int r = 0; r < 4; ++r) {
          int k = pf * 16 + lg * 4 + r;
          float v = acc[pf][of][r] + bia[of];
          sc[pf][r] = (k < cnt) ? v : -1e9f;
        }
      float m = sc[0][0];
#pragma unroll
      for (int pf = 0; pf < 2; ++pf)
#pragma unroll
        for (int r = 0; r < 4; ++r) m = fmaxf(m, sc[pf][r]);
      m = fmaxf(m, __shfl_xor(m, 16));
      m = fmaxf(m, __shfl_xor(m, 32));
      float den = 0.f, con = 0.f;
      const int q16 = of * 2 + (l15 >> 3);  // 8-short chunk of channel o
#pragma unroll
      for (int pf = 0; pf < 2; ++pf)
#pragma unroll
        for (int r = 0; r < 4; ++r) {
          float e = __expf(sc[pf][r] - m);
          const int k = pf * 16 + lg * 4 + r;
          const int qs = q16 ^ ((k & 6) >> 1);
          float g = bf2f(slice[k * 32 + qs * 8 + (l15 & 7)]);
          g = fmaxf(s3v[of] * g + t3v[of], 0.f);
          den += e; con += e * g;
        }
      den += __shfl_xor(den, 16); con += __shfl_xor(con, 16);
      den += __shfl_xor(den, 32); con += __shfl_xor(con, 32);
      if (lg == 0)
        out[(size_t)(b * 256 + o) * NN + n] = con / den;
    }
  }
}

// ---------------- launch ----------------
extern "C" void kernel_launch(void* const* d_in, const int* in_sizes, int n_in,
                              void* d_out, int out_size, void* d_ws, size_t ws_size,
                              hipStream_t stream) {
  const float* feat = (const float*)d_in[0];
  const float* gf   = (const float*)d_in[1];
  const float* gfo  = (const float*)d_in[2];
  const int*   cnt  = (const int*)d_in[3];
  const float* W_fc = (const float*)d_in[4];
  const float* b_fc = (const float*)d_in[5];
  const float* W_gc = (const float*)d_in[6];
  const float* b_gc = (const float*)d_in[7];
  const float* g1   = (const float*)d_in[8];
  const float* be1  = (const float*)d_in[9];
  const float* W_w1 = (const float*)d_in[10];
  const float* b_w1 = (const float*)d_in[11];
  const float* g2   = (const float*)d_in[12];
  const float* be2  = (const float*)d_in[13];
  const float* W_w2 = (const float*)d_in[14];
  const float* b_w2 = (const float*)d_in[15];
  const float* W_fo = (const float*)d_in[16];
  const float* b_fo = (const float*)d_in[17];
  const float* g3   = (const float*)d_in[18];
  const float* be3  = (const float*)d_in[19];
  float* out = (float*)d_out;
  char* ws = (char*)d_ws;

  constexpr size_t ST1 = 0, ST2 = 1024, ST3 = 2048;
  constexpr size_t WFC = 4096;
  constexpr size_t WGC = WFC + 32768;
  constexpr size_t WFO = WGC + 32768;
  constexpr size_t W1P = WFO + 131072;
  constexpr size_t B1P = W1P + 524288;
  constexpr size_t W2P = B1P + 4096;
  constexpr size_t B2P = W2P + 524288;
  constexpr size_t S3T = B2P + 4096;
  constexpr size_t R1  = 2097152;
  constexpr size_t X2  = R1 + 2097152;
  constexpr size_t R2  = X2 + 134217728;
  constexpr size_t GOR = R2;  // go_raw overwrites r2 (written after K4 consumed r2)
  constexpr size_t WS_NEED = GOR + 134217728;
  if (ws_size < WS_NEED) return;

  float* st1 = (float*)(ws + ST1);
  float* st2 = (float*)(ws + ST2);
  float* st3 = (float*)(ws + ST3);
  unsigned short* wfc = (unsigned short*)(ws + WFC);
  unsigned short* wgc = (unsigned short*)(ws + WGC);
  unsigned short* wfo = (unsigned short*)(ws + WFO);
  unsigned short* w1p = (unsigned short*)(ws + W1P);
  float* b1p = (float*)(ws + B1P);
  unsigned short* w2p = (unsigned short*)(ws + W2P);
  float* b2p = (float*)(ws + B2P);
  float* s3t = (float*)(ws + S3T);
  unsigned short* r1 = (unsigned short*)(ws + R1);
  unsigned short* x2 = (unsigned short*)(ws + X2);
  unsigned short* r2 = (unsigned short*)(ws + R2);
  unsigned short* gor = (unsigned short*)(ws + GOR);

  hipMemsetAsync(ws, 0, 3072, stream);
  prep_kern<<<384, 256, 0, stream>>>(W_fc, W_gc, W_fo, wfc, wgc, wfo);

  // K1: feat1 = relu(W_fc@feat+b) -> r1 [b][n][128], stats1 groups 0..15
  wgemm_kern<128, 128, 0, true><<<dim3(4 * 32), 512, 0, stream>>>(
      feat, nullptr, wfc, b_fc, r1, st1, 0, NN, NN / 16, 32);
  // K2: gfeat1 = relu(W_gc@gf+b) -> r2 [b][p][128], stats1 groups 16..31
  wgemm_kern<128, 128, 0, true><<<dim3(4 * 128), 512, 0, stream>>>(
      gf, nullptr, wgc, b_gc, r2, st1, 16, PP, PP / 16, 128);

  fold1_kern<<<4, 256, 0, stream>>>(st1, g1, be1, W_w1, b_w1, w1p, b1p);

  // K4: x2 = relu(W1'(GN1-folded) @ concat(r1,r2)) -> x2, stats2
  wgemm_kern<256, 256, 1, true><<<dim3(4 * 128), 512, 0, stream>>>(
      r1, r2, w1p, b1p, x2, st2, 0, PP, PP / 16, 128);

  // K3: go_raw = W_fo@gfo+b (no relu) -> gor (overwrites r2), stats3 on raw
  wgemm_kern<256, 256, 0, false><<<dim3(4 * 128), 512, 0, stream>>>(
      gfo, nullptr, wfo, b_fo, gor, st3, 0, PP, PP / 16, 128);

  fold23_kern<<<4, 256, 0, stream>>>(st2, st3, g2, be2, W_w2, b_w2, g3, be3, w2p, b2p, s3t);

  // K5: scores (GN2-folded) + mask + softmax + sum_k relu(GN3(go))*w -> out
  k5_kern<<<dim3(4 * 128), 512, 0, stream>>>(x2, gor, w2p, b2p, s3t, cnt, out, NN, 128);
}

// Round 10
// 1070.772 us; speedup vs baseline: 1.3785x; 1.3785x over previous
//
#include <hip/hip_runtime.h>
#include <stdint.h>

#define DEVI __device__ __forceinline__

typedef __attribute__((ext_vector_type(4))) int    i32x4;
typedef __attribute__((ext_vector_type(4))) float  f32x4;
typedef __attribute__((ext_vector_type(8))) __bf16 bf16x8;

static constexpr int BB = 4, NN = 2048, KK = 32, PP = NN * KK;  // P per batch
static constexpr float GEPS = 1e-5f;

DEVI unsigned short f2bf(float f) {
  unsigned u = __builtin_bit_cast(unsigned, f);
  return (unsigned short)((u + 0x7FFFu + ((u >> 16) & 1u)) >> 16);
}
DEVI float bf2f(unsigned short h) {
  unsigned u = (unsigned)h << 16;
  return __builtin_bit_cast(float, u);
}
DEVI uint2 pack4(float a, float b, float c, float d) {
  return make_uint2((unsigned)f2bf(a) | ((unsigned)f2bf(b) << 16),
                    (unsigned)f2bf(c) | ((unsigned)f2bf(d) << 16));
}
DEVI void mfma16(f32x4& d, i32x4 a, i32x4 b) {
  // A[m=lane&15][k=8*(lane>>4)+j], B[k][n=lane&15], D[m=(lane>>4)*4+reg][n=lane&15].
  d = __builtin_amdgcn_mfma_f32_16x16x32_bf16(
      __builtin_bit_cast(bf16x8, a), __builtin_bit_cast(bf16x8, b), d, 0, 0, 0);
}

// ---------------- prep: convert f32 weights to bf16 ----------------
__global__ void prep_kern(const float* Wfc, const float* Wgc, const float* Wfo,
                          unsigned short* dWfc, unsigned short* dWgc, unsigned short* dWfo) {
  int i = blockIdx.x * 256 + threadIdx.x;
  if (i < 16384)       dWfc[i] = f2bf(Wfc[i]);
  else if (i < 32768)  dWgc[i - 16384] = f2bf(Wgc[i - 16384]);
  else if (i < 98304)  dWfo[i - 32768] = f2bf(Wfo[i - 32768]);
}

// ---------------- cooperative-staged fused GEMM ----------------
// out[b][p][COUT](bf16) = act(W[COUT][CIN] @ in[b][CIN][p] + bias)
// 512 thr = 8 waves. Tile = TP = 4096/CIN positions x CIN channels (8 KB bf16),
// staged ONCE per block (each thread stores one uint4) — kills the R6-R9
// disease (every wave privately re-loading the tile: FETCH was 8x input).
// LDS dbuf + register prefetch of tile t+1 issued before the barrier (T14);
// raw s_barrier (no vmcnt drain; LDS is issue-ordered per CU, m201 pattern).
// W resident in regs/AGPRs. Output transposed via wave-private LDS slice ->
// coalesced 64B stores.
// LDS tile layout: row p (TP rows of CIN shorts), 8-short chunk oct stored at
// slot oct^(p&15) — same XOR map on write and read.
// MODE 0: srcA = f32 channel-major [b][CIN][P]  (8 coalesced dwords + pack)
// MODE 1: srcA = r1 bf16 [b][n][128] (k-broadcast), srcB = r2 bf16 [b][p][128]
template<int CIN, int COUT, int MODE, bool RELU>
__global__ __launch_bounds__(512)
void wgemm_kern(const void* __restrict__ srcA, const void* __restrict__ srcB,
                const unsigned short* __restrict__ Wmat, const float* __restrict__ bias,
                unsigned short* __restrict__ out, float* __restrict__ stats, int group_base,
                int P, int tiles_per_b, int nblk) {
  constexpr int TP  = 4096 / CIN;            // positions per tile (32 or 16)
  constexpr int NF  = TP / 16;               // n-fragments (2 or 1)
  constexpr int MW  = (COUT == 256) ? 32 : 16;
  constexpr int MF  = MW / 16;               // m-fragments
  constexpr int KS  = CIN / 32;              // k-steps
  constexpr int OCTM = CIN / 8 - 1;          // octet mask
  __shared__ unsigned short tile[2][TP * CIN];
  __shared__ unsigned short osl[8 * 16 * MW];

  const int tid = threadIdx.x;
  const int lane = tid & 63, w = tid >> 6;
  const int l15 = lane & 15, lg = lane >> 4;
  const int b = blockIdx.x / nblk, blk = blockIdx.x % nblk;
  const int tpb = tiles_per_b / nblk;

  const unsigned short* Wb = (MODE == 1) ? (Wmat + (size_t)b * COUT * CIN) : Wmat;
  const float* biasb = (MODE == 1) ? (bias + b * COUT) : bias;
  const float* src0 = (const float*)srcA + (size_t)b * CIN * P;
  const unsigned short* r1b = (const unsigned short*)srcA + (size_t)b * NN * 128;
  const unsigned short* r2b = (const unsigned short*)srcB + (size_t)b * PP * 128;

  // W fragments resident for the whole kernel
  i32x4 a[KS][MF];
#pragma unroll
  for (int ks = 0; ks < KS; ++ks)
#pragma unroll
    for (int mf = 0; mf < MF; ++mf)
      a[ks][mf] = *(const i32x4*)(Wb + (size_t)(w * MW + mf * 16 + l15) * CIN + ks * 32 + lg * 8);

  f32x4 bi[MF];
#pragma unroll
  for (int mf = 0; mf < MF; ++mf)
    bi[mf] = *(const f32x4*)(biasb + w * MW + mf * 16 + lg * 4);

  float ssum[MF], ssq[MF];
#pragma unroll
  for (int mf = 0; mf < MF; ++mf) { ssum[mf] = 0.f; ssq[mf] = 0.f; }

  // staging maps (each thread stores exactly one uint4 = 8 bf16)
  const int sp0 = tid & (TP - 1), oct0 = tid / TP;   // MODE 0: pos-fast
  const int rr1 = tid >> 5, ck1 = tid & 31;          // MODE 1: chunk-fast
  float pv0[8];
  uint4 pv1;

  auto issue = [&](int tt) {
    const int p0 = tt * TP;
    if constexpr (MODE == 0) {
#pragma unroll
      for (int j = 0; j < 8; ++j)
        pv0[j] = src0[(size_t)(oct0 * 8 + j) * (size_t)P + p0 + sp0];
    } else {
      if (ck1 < 16) {
        pv1 = *(const uint4*)(r1b + (size_t)(p0 >> 5) * 128 + ck1 * 8);
      } else {
        pv1 = *(const uint4*)(r2b + (size_t)(p0 + rr1) * 128 + (ck1 - 16) * 8);
      }
    }
  };
  auto stage = [&](int cb) {
    unsigned short* tl = tile[cb];
    if constexpr (MODE == 0) {
      uint2 lo = pack4(pv0[0], pv0[1], pv0[2], pv0[3]);
      uint2 hi = pack4(pv0[4], pv0[5], pv0[6], pv0[7]);
      const int os = (oct0 ^ (sp0 & 15)) & OCTM;
      *(uint4*)&tl[sp0 * CIN + os * 8] = make_uint4(lo.x, lo.y, hi.x, hi.y);
    } else {
      const int os = (ck1 ^ rr1) & OCTM;
      *(uint4*)&tl[rr1 * CIN + os * 8] = pv1;
    }
  };

  int cb = 0;
  issue(blk * tpb);
  for (int t = blk * tpb; t < (blk + 1) * tpb; ++t) {
    stage(cb);
    if (t + 1 < (blk + 1) * tpb) issue(t + 1);
    __builtin_amdgcn_s_barrier();  // LDS issue-ordered; globals stay in flight
    const unsigned short* tl = tile[cb];
    const int p0 = t * TP;

    f32x4 acc[MF][NF];
#pragma unroll
    for (int mf = 0; mf < MF; ++mf)
#pragma unroll
      for (int nf = 0; nf < NF; ++nf) acc[mf][nf] = f32x4{0.f, 0.f, 0.f, 0.f};

#pragma unroll
    for (int ks = 0; ks < KS; ++ks) {
      i32x4 b4[NF];
#pragma unroll
      for (int nf = 0; nf < NF; ++nf) {
        const int row = nf * 16 + l15;
        const int os = ((ks * 4 + lg) ^ (row & 15)) & OCTM;
        b4[nf] = *(const i32x4*)&tl[row * CIN + os * 8];
      }
#pragma unroll
      for (int mf = 0; mf < MF; ++mf)
#pragma unroll
        for (int nf = 0; nf < NF; ++nf) mfma16(acc[mf][nf], a[ks][mf], b4[nf]);
    }

    // epilogue per nf: bias(+relu), stats, private-slice transpose, 64B stores
    unsigned short* slice = &osl[w * 16 * MW];
#pragma unroll
    for (int nf = 0; nf < NF; ++nf) {
#pragma unroll
      for (int mf = 0; mf < MF; ++mf) {
        float y0 = acc[mf][nf][0] + bi[mf][0];
        float y1 = acc[mf][nf][1] + bi[mf][1];
        float y2 = acc[mf][nf][2] + bi[mf][2];
        float y3 = acc[mf][nf][3] + bi[mf][3];
        if (RELU) {
          y0 = fmaxf(y0, 0.f); y1 = fmaxf(y1, 0.f);
          y2 = fmaxf(y2, 0.f); y3 = fmaxf(y3, 0.f);
        }
        ssum[mf] += y0 + y1 + y2 + y3;
        ssq[mf] += y0 * y0 + y1 * y1 + y2 * y2 + y3 * y3;
        if constexpr (MW == 32) {
          const int c = (mf * 4 + lg) ^ (l15 & 6);
          *(uint2*)&slice[l15 * 32 + c * 4] = pack4(y0, y1, y2, y3);
        } else {
          const int c = lg ^ (l15 & 2);
          *(uint2*)&slice[l15 * 16 + c * 4] = pack4(y0, y1, y2, y3);
        }
      }
      if constexpr (MW == 32) {
        const int pos = lane >> 2, q = lane & 3;
        const int qs = q ^ ((pos & 6) >> 1);
        uint4 val = *(const uint4*)&slice[pos * 32 + qs * 8];
        *(uint4*)(out + ((size_t)b * P + p0 + nf * 16 + pos) * COUT + w * 32 + q * 8) = val;
      } else {
        const int pos = lane >> 2, cc = lane & 3;
        const int cs = cc ^ (pos & 2);
        uint2 val = *(const uint2*)&slice[pos * 16 + cs * 4];
        *(uint2*)(out + ((size_t)b * P + p0 + nf * 16 + pos) * COUT + w * 16 + cc * 4) = val;
      }
    }
    cb ^= 1;
  }

  // stats reduction -> global atomics
#pragma unroll
  for (int mf = 0; mf < MF; ++mf) {
    float s = ssum[mf], q = ssq[mf];
#pragma unroll
    for (int d = 1; d < 16; d <<= 1) { s += __shfl_xor(s, d); q += __shfl_xor(q, d); }
    if (l15 == 0) {
      int g = group_base + ((w * MW + mf * 16 + lg * 4) >> 3);
      atomicAdd(&stats[(b * 32 + g) * 2 + 0], s);
      atomicAdd(&stats[(b * 32 + g) * 2 + 1], q);
    }
  }
}

// ---------------- fold kernels ----------------
__global__ void fold1_kern(const float* st1, const float* g1, const float* be1,
                           const float* W_w1, const float* b_w1,
                           unsigned short* W1p, float* b1p) {
  int b = blockIdx.x, tid = threadIdx.x;
  __shared__ float s_l[256], t_l[256];
  {
    int c = tid, g = c >> 3;
    float cnt = (g < 16) ? (8.f * NN) : (8.f * NN * KK);
    float su = st1[(b * 32 + g) * 2], sq = st1[(b * 32 + g) * 2 + 1];
    float mean = su / cnt;
    float var = fmaxf(sq / cnt - mean * mean, 0.f);
    float s = g1[c] * rsqrtf(var + GEPS);
    s_l[c] = s; t_l[c] = be1[c] - mean * s;
  }
  __syncthreads();
  int o = tid;
  float acc = b_w1[o];
  for (int c4 = 0; c4 < 64; ++c4) {
    float4 wv = *(const float4*)(W_w1 + o * 256 + c4 * 4);
    *(uint2*)&W1p[((size_t)b * 256 + o) * 256 + c4 * 4] =
        pack4(wv.x * s_l[c4 * 4], wv.y * s_l[c4 * 4 + 1],
              wv.z * s_l[c4 * 4 + 2], wv.w * s_l[c4 * 4 + 3]);
    acc += wv.x * t_l[c4 * 4] + wv.y * t_l[c4 * 4 + 1] +
           wv.z * t_l[c4 * 4 + 2] + wv.w * t_l[c4 * 4 + 3];
  }
  b1p[b * 256 + o] = acc;
}

__global__ void fold23_kern(const float* st2, const float* st3,
                            const float* g2, const float* be2,
                            const float* W_w2, const float* b_w2,
                            const float* g3, const float* be3,
                            unsigned short* W2p, float* b2p, float* s3t3) {
  int b = blockIdx.x, tid = threadIdx.x;
  __shared__ float s_l[256], t_l[256];
  {
    int c = tid, g = c >> 3;
    float cnt = 8.f * NN * KK;
    float su = st2[(b * 32 + g) * 2], sq = st2[(b * 32 + g) * 2 + 1];
    float mean = su / cnt;
    float var = fmaxf(sq / cnt - mean * mean, 0.f);
    float s = g2[c] * rsqrtf(var + GEPS);
    s_l[c] = s; t_l[c] = be2[c] - mean * s;

    float su3 = st3[(b * 32 + g) * 2], sq3 = st3[(b * 32 + g) * 2 + 1];
    float mean3 = su3 / cnt;
    float var3 = fmaxf(sq3 / cnt - mean3 * mean3, 0.f);
    float s3 = g3[c] * rsqrtf(var3 + GEPS);
    s3t3[(b * 256 + c) * 2 + 0] = s3;
    s3t3[(b * 256 + c) * 2 + 1] = be3[c] - mean3 * s3;
  }
  __syncthreads();
  int o = tid;
  float acc = b_w2[o];
  for (int c4 = 0; c4 < 64; ++c4) {
    float4 wv = *(const float4*)(W_w2 + o * 256 + c4 * 4);
    *(uint2*)&W2p[((size_t)b * 256 + o) * 256 + c4 * 4] =
        pack4(wv.x * s_l[c4 * 4], wv.y * s_l[c4 * 4 + 1],
              wv.z * s_l[c4 * 4 + 2], wv.w * s_l[c4 * 4 + 3]);
    acc += wv.x * t_l[c4 * 4] + wv.y * t_l[c4 * 4 + 1] +
           wv.z * t_l[c4 * 4 + 2] + wv.w * t_l[c4 * 4 + 3];
  }
  b2p[b * 256 + o] = acc;
}

// ---------------- K5: scores GEMM + masked softmax + weighted sum ----------------
// 32-pos tiles (= one n). x2 tile cooperatively staged (once per block, dbuf,
// prefetch); W2 resident; gor staged per-wave into private slice (as before).
__global__ __launch_bounds__(512)
void k5_kern(const unsigned short* __restrict__ x2t, const unsigned short* __restrict__ gor,
             const unsigned short* __restrict__ W2p, const float* __restrict__ b2p,
             const float* __restrict__ s3t3, const int* __restrict__ count,
             float* __restrict__ out, int tiles_per_b, int nblk) {
  __shared__ unsigned short xt[2][32 * 256];   // 32 KB
  __shared__ unsigned short gsl[8 * 32 * 32];  // 16 KB, per-wave slices
  const int tid = threadIdx.x, lane = tid & 63, w = tid >> 6;
  const int l15 = lane & 15, lg = lane >> 4;
  const int b = blockIdx.x / nblk, blk = blockIdx.x % nblk;
  const int tpb = tiles_per_b / nblk;
  const int wch = w * 32;

  const unsigned short* Wb = W2p + (size_t)b * 65536;

  i32x4 wb[8][2];
#pragma unroll
  for (int ks = 0; ks < 8; ++ks)
#pragma unroll
    for (int of = 0; of < 2; ++of)
      wb[ks][of] = *(const i32x4*)(Wb + (size_t)(wch + of * 16 + l15) * 256 + ks * 32 + lg * 8);

  float bia[2], s3v[2], t3v[2];
#pragma unroll
  for (int of = 0; of < 2; ++of) {
    int o = wch + of * 16 + l15;
    bia[of] = b2p[b * 256 + o];
    s3v[of] = s3t3[(b * 256 + o) * 2 + 0];
    t3v[of] = s3t3[(b * 256 + o) * 2 + 1];
  }

  const unsigned short* xb = x2t + (size_t)b * PP * 256;
  const unsigned short* gb = gor + (size_t)b * PP * 256;
  unsigned short* slice = &gsl[w * 32 * 32];

  const int rr = tid >> 4, ck2 = tid & 15;  // x2 staging: row 0..31, 2 chunks
  uint4 pvx[2], pvg[2];
  auto issue = [&](int tt) {
    const int p0 = tt * 32;
#pragma unroll
    for (int h = 0; h < 2; ++h)
      pvx[h] = *(const uint4*)(xb + (size_t)(p0 + rr) * 256 + (ck2 + h * 16) * 8);
#pragma unroll
    for (int h = 0; h < 2; ++h) {
      const int pos = h * 16 + (lane >> 2), q = lane & 3;
      pvg[h] = *(const uint4*)(gb + (size_t)(p0 + pos) * 256 + wch + q * 8);
    }
  };
  auto stage = [&](int cb) {
    unsigned short* tl = xt[cb];
#pragma unroll
    for (int h = 0; h < 2; ++h) {
      const int oct = ck2 + h * 16;
      const int os = (oct ^ (rr & 15)) & 31;
      *(uint4*)&tl[rr * 256 + os * 8] = pvx[h];
    }
#pragma unroll
    for (int h = 0; h < 2; ++h) {
      const int pos = h * 16 + (lane >> 2), q = lane & 3;
      const int qs = q ^ ((pos & 6) >> 1);
      *(uint4*)&slice[pos * 32 + qs * 8] = pvg[h];
    }
  };

  int cb = 0;
  issue(blk * tpb);
  for (int t = blk * tpb; t < (blk + 1) * tpb; ++t) {
    stage(cb);
    if (t + 1 < (blk + 1) * tpb) issue(t + 1);
    __builtin_amdgcn_s_barrier();
    const unsigned short* tl = xt[cb];
    const int n = t;

    f32x4 acc[2][2];  // [pf][of]
#pragma unroll
    for (int pf = 0; pf < 2; ++pf)
#pragma unroll
      for (int of = 0; of < 2; ++of) acc[pf][of] = f32x4{0.f, 0.f, 0.f, 0.f};

#pragma unroll
    for (int ks = 0; ks < 8; ++ks) {
      i32x4 af[2];
#pragma unroll
      for (int pf = 0; pf < 2; ++pf) {
        const int row = pf * 16 + l15;
        const int os = ((ks * 4 + lg) ^ (row & 15)) & 31;
        af[pf] = *(const i32x4*)&tl[row * 256 + os * 8];
      }
#pragma unroll
      for (int pf = 0; pf < 2; ++pf)
#pragma unroll
        for (int of = 0; of < 2; ++of) mfma16(acc[pf][of], af[pf], wb[ks][of]);
    }

    const int cnt = max(count[b * NN + n], 1);
#pragma unroll
    for (int of = 0; of < 2; ++of) {
      const int o = wch + of * 16 + l15;
      float sc[2][4];
#pragma unroll
      for (int pf = 0; pf < 2; ++pf)
#pragma unroll
        for (int r = 0; r < 4; ++r) {
          int k = pf * 16 + lg * 4 + r;
          float v = acc[pf][of][r] + bia[of];
          sc[pf][r] = (k < cnt) ? v : -1e9f;
        }
      float m = sc[0][0];
#pragma unroll
      for (int pf = 0; pf < 2; ++pf)
#pragma unroll
        for (int r = 0; r < 4; ++r) m = fmaxf(m, sc[pf][r]);
      m = fmaxf(m, __shfl_xor(m, 16));
      m = fmaxf(m, __shfl_xor(m, 32));
      float den = 0.f, con = 0.f;
      const int q16 = of * 2 + (l15 >> 3);
#pragma unroll
      for (int pf = 0; pf < 2; ++pf)
#pragma unroll
        for (int r = 0; r < 4; ++r) {
          float e = __expf(sc[pf][r] - m);
          const int k = pf * 16 + lg * 4 + r;
          const int qs = q16 ^ ((k & 6) >> 1);
          float g = bf2f(slice[k * 32 + qs * 8 + (l15 & 7)]);
          g = fmaxf(s3v[of] * g + t3v[of], 0.f);
          den += e; con += e * g;
        }
      den += __shfl_xor(den, 16); con += __shfl_xor(con, 16);
      den += __shfl_xor(den, 32); con += __shfl_xor(con, 32);
      if (lg == 0)
        out[(size_t)(b * 256 + o) * NN + n] = con / den;
    }
    cb ^= 1;
  }
}

// ---------------- launch ----------------
extern "C" void kernel_launch(void* const* d_in, const int* in_sizes, int n_in,
                              void* d_out, int out_size, void* d_ws, size_t ws_size,
                              hipStream_t stream) {
  const float* feat = (const float*)d_in[0];
  const float* gf   = (const float*)d_in[1];
  const float* gfo  = (const float*)d_in[2];
  const int*   cnt  = (const int*)d_in[3];
  const float* W_fc = (const float*)d_in[4];
  const float* b_fc = (const float*)d_in[5];
  const float* W_gc = (const float*)d_in[6];
  const float* b_gc = (const float*)d_in[7];
  const float* g1   = (const float*)d_in[8];
  const float* be1  = (const float*)d_in[9];
  const float* W_w1 = (const float*)d_in[10];
  const float* b_w1 = (const float*)d_in[11];
  const float* g2   = (const float*)d_in[12];
  const float* be2  = (const float*)d_in[13];
  const float* W_w2 = (const float*)d_in[14];
  const float* b_w2 = (const float*)d_in[15];
  const float* W_fo = (const float*)d_in[16];
  const float* b_fo = (const float*)d_in[17];
  const float* g3   = (const float*)d_in[18];
  const float* be3  = (const float*)d_in[19];
  float* out = (float*)d_out;
  char* ws = (char*)d_ws;

  constexpr size_t ST1 = 0, ST2 = 1024, ST3 = 2048;
  constexpr size_t WFC = 4096;
  constexpr size_t WGC = WFC + 32768;
  constexpr size_t WFO = WGC + 32768;
  constexpr size_t W1P = WFO + 131072;
  constexpr size_t B1P = W1P + 524288;
  constexpr size_t W2P = B1P + 4096;
  constexpr size_t B2P = W2P + 524288;
  constexpr size_t S3T = B2P + 4096;
  constexpr size_t R1  = 2097152;
  constexpr size_t X2  = R1 + 2097152;
  constexpr size_t R2  = X2 + 134217728;
  constexpr size_t GOR = R2;  // go_raw overwrites r2 (written after K4 consumed r2)
  constexpr size_t WS_NEED = GOR + 134217728;
  if (ws_size < WS_NEED) return;

  float* st1 = (float*)(ws + ST1);
  float* st2 = (float*)(ws + ST2);
  float* st3 = (float*)(ws + ST3);
  unsigned short* wfc = (unsigned short*)(ws + WFC);
  unsigned short* wgc = (unsigned short*)(ws + WGC);
  unsigned short* wfo = (unsigned short*)(ws + WFO);
  unsigned short* w1p = (unsigned short*)(ws + W1P);
  float* b1p = (float*)(ws + B1P);
  unsigned short* w2p = (unsigned short*)(ws + W2P);
  float* b2p = (float*)(ws + B2P);
  float* s3t = (float*)(ws + S3T);
  unsigned short* r1 = (unsigned short*)(ws + R1);
  unsigned short* x2 = (unsigned short*)(ws + X2);
  unsigned short* r2 = (unsigned short*)(ws + R2);
  unsigned short* gor = (unsigned short*)(ws + GOR);

  hipMemsetAsync(ws, 0, 3072, stream);
  prep_kern<<<384, 256, 0, stream>>>(W_fc, W_gc, W_fo, wfc, wgc, wfo);

  // K1: feat1 = relu(W_fc@feat+b) -> r1 [b][n][128], stats1 groups 0..15 (TP=32)
  wgemm_kern<128, 128, 0, true><<<dim3(4 * 16), 512, 0, stream>>>(
      feat, nullptr, wfc, b_fc, r1, st1, 0, NN, NN / 32, 16);
  // K2: gfeat1 = relu(W_gc@gf+b) -> r2 [b][p][128], stats1 groups 16..31 (TP=32)
  wgemm_kern<128, 128, 0, true><<<dim3(4 * 128), 512, 0, stream>>>(
      gf, nullptr, wgc, b_gc, r2, st1, 16, PP, PP / 32, 128);

  fold1_kern<<<4, 256, 0, stream>>>(st1, g1, be1, W_w1, b_w1, w1p, b1p);

  // K4: x2 = relu(W1'(GN1-folded) @ concat(r1,r2)) -> x2, stats2 (TP=16)
  wgemm_kern<256, 256, 1, true><<<dim3(4 * 256), 512, 0, stream>>>(
      r1, r2, w1p, b1p, x2, st2, 0, PP, PP / 16, 256);

  // K3: go_raw = W_fo@gfo+b (no relu) -> gor (overwrites r2), stats3 (TP=16)
  wgemm_kern<256, 256, 0, false><<<dim3(4 * 256), 512, 0, stream>>>(
      gfo, nullptr, wfo, b_fo, gor, st3, 0, PP, PP / 16, 256);

  fold23_kern<<<4, 256, 0, stream>>>(st2, st3, g2, be2, W_w2, b_w2, g3, be3, w2p, b2p, s3t);

  // K5: scores (GN2-folded) + mask + softmax + sum_k relu(GN3(go))*w -> out
  k5_kern<<<dim3(4 * 128), 512, 0, stream>>>(x2, gor, w2p, b2p, s3t, cnt, out, PP / 32, 128);
}